// Round 2
// baseline (663.736 us; speedup 1.0000x reference)
//
#include <hip/hip_runtime.h>
#include <math.h>

#define NN 50000
#define DD 128
#define KK 16
#define CC 8

// ---- ws layout (bytes) ----
#define A_OFF    0u
#define B_OFF    (NN*DD*4u)               // 25,600,000
#define CENT_OFF (2u*NN*DD*4u)            // 51,200,000
#define ZOLD_OFF (CENT_OFF + NN*4u)
#define F1_OFF   (ZOLD_OFF + NN*4u)
#define F2_OFF   (F1_OFF + NN*4u)
#define SU_OFF   (F2_OFF + NN*4u)         // 2 x u32 (exact f1 sums)
#define SD_OFF   (SU_OFF + 8u)            // 2 x double (f2 sums)
#define OACC_OFF (SD_OFF + 16u)           // 8 x double (output accum)

// ---------------- feat @ W_gcn -> A ----------------
// 64 nodes/block, W (64KB) + feat tile (33KB) in LDS; thread = 4 nodes x 8 cols.
__global__ __launch_bounds__(256) void k_gemm(const float* __restrict__ feat,
    const float* __restrict__ W, float* __restrict__ A, double* __restrict__ oacc)
{
    __shared__ __align__(16) float sW[DD*DD];
    __shared__ float sF[64][DD+1];
    const int t = threadIdx.x;
    const int base = blockIdx.x * 64;
    if (blockIdx.x == 0 && t < CC) oacc[t] = 0.0;

    const float4* W4 = (const float4*)W;
    float4* sW4 = (float4*)sW;
    #pragma unroll
    for (int i = 0; i < 16; ++i) sW4[t + i*256] = W4[t + i*256];

    const float4* F4 = (const float4*)feat;
    #pragma unroll
    for (int e = t; e < 64*32; e += 256) {
        int row = e >> 5, q = e & 31;
        float4 v = make_float4(0.f,0.f,0.f,0.f);
        if (base + row < NN) v = F4[(size_t)(base + row)*32 + q];
        sF[row][q*4+0] = v.x; sF[row][q*4+1] = v.y;
        sF[row][q*4+2] = v.z; sF[row][q*4+3] = v.w;
    }
    __syncthreads();

    const int cg = t & 15;       // cols cg*8 .. cg*8+7
    const int ng = t >> 4;       // nodes ng*4 .. ng*4+3
    const int cb = cg * 8;
    float acc[4][8];
    #pragma unroll
    for (int j=0;j<4;++j)
        #pragma unroll
        for (int c=0;c<8;++c) acc[j][c]=0.f;

    #pragma unroll 4
    for (int d = 0; d < DD; ++d) {
        float4 wa = *(const float4*)&sW[d*DD + cb];
        float4 wb = *(const float4*)&sW[d*DD + cb + 4];
        #pragma unroll
        for (int j=0;j<4;++j) {
            float f = sF[ng*4+j][d];
            acc[j][0] += f*wa.x; acc[j][1] += f*wa.y;
            acc[j][2] += f*wa.z; acc[j][3] += f*wa.w;
            acc[j][4] += f*wb.x; acc[j][5] += f*wb.y;
            acc[j][6] += f*wb.z; acc[j][7] += f*wb.w;
        }
    }
    #pragma unroll
    for (int j=0;j<4;++j) {
        int node = base + ng*4 + j;
        if (node < NN) {
            float4* dst = (float4*)&A[(size_t)node*DD + cb];
            dst[0] = make_float4(acc[j][0],acc[j][1],acc[j][2],acc[j][3]);
            dst[1] = make_float4(acc[j][4],acc[j][5],acc[j][6],acc[j][7]);
        }
    }
}

// ---------------- h0 = gather-sum(A) + b_gcn; zold = 1 ----------------
__global__ __launch_bounds__(256) void k_agg0(const float4* __restrict__ A4,
    const int* __restrict__ nb, const float* __restrict__ bg,
    float4* __restrict__ H4, float* __restrict__ zold)
{
    const int t = threadIdx.x;
    const int node = blockIdx.x*8 + (t>>5);
    const int q = t & 31;
    if (node >= NN) return;
    const int* nbi = nb + node*KK;
    int idx[KK];
    #pragma unroll
    for (int k=0;k<KK;++k) idx[k] = nbi[k];
    float4 acc = ((const float4*)bg)[q];
    #pragma unroll
    for (int k=0;k<KK;++k) {
        float4 v = A4[(size_t)idx[k]*32 + q];
        acc.x += v.x; acc.y += v.y; acc.z += v.z; acc.w += v.w;
    }
    H4[(size_t)node*32 + q] = acc;
    if (q == 0) zold[node] = 1.0f;
}

// ---------------- center = argmax(h@Wy+by) (softmax skipped: monotonic) ----------------
__global__ __launch_bounds__(256) void k_center(const float* __restrict__ H,
    const float* __restrict__ Wy, const float* __restrict__ by,
    int* __restrict__ center, unsigned* __restrict__ su, double* __restrict__ sd)
{
    const int t = threadIdx.x;
    if (blockIdx.x == 0) {          // zero the per-iteration stat accumulators
        if (t < 2) su[t] = 0u;
        if (t >= 2 && t < 4) sd[t-2] = 0.0;
    }
    __shared__ float sH[64][DD+1];
    __shared__ __align__(16) float sWy[DD*CC];
    __shared__ float sby[CC];
    const int base = blockIdx.x * 64;
    const float4* H4 = (const float4*)H;
    #pragma unroll
    for (int e = t; e < 64*32; e += 256) {
        int row = e >> 5, q = e & 31;
        float4 v = make_float4(0.f,0.f,0.f,0.f);
        if (base + row < NN) v = H4[(size_t)(base+row)*32 + q];
        sH[row][q*4+0] = v.x; sH[row][q*4+1] = v.y;
        sH[row][q*4+2] = v.z; sH[row][q*4+3] = v.w;
    }
    ((float4*)sWy)[t] = ((const float4*)Wy)[t & 255];   // 256 float4 == 1024 floats
    if (t < CC) sby[t] = by[t];
    __syncthreads();

    const int nl = t >> 2;          // node-local 0..63
    const int c0 = (t & 3) * 2;     // this lane handles classes c0, c0+1
    float a0 = 0.f, a1 = 0.f;
    #pragma unroll 8
    for (int d = 0; d < DD; ++d) {
        float f = sH[nl][d];
        a0 += f * sWy[d*CC + c0];
        a1 += f * sWy[d*CC + c0 + 1];
    }
    a0 += sby[c0]; a1 += sby[c0+1];
    float bv = a0; int bi = c0;
    if (a1 > bv) { bv = a1; bi = c0 + 1; }
    #pragma unroll
    for (int off = 1; off < 4; off <<= 1) {
        float ov = __shfl_xor(bv, off, 64);
        int   oi = __shfl_xor(bi, off, 64);
        // first-occurrence argmax: on tie keep smaller index
        if (ov > bv || (ov == bv && oi < bi)) { bv = ov; bi = oi; }
    }
    const int node = base + nl;
    if ((t & 3) == 0 && node < NN) center[node] = bi;
}

// ---------------- f1, f2 per node + global sums (u32 exact / f64) ----------------
__global__ __launch_bounds__(256) void k_stats(const int* __restrict__ center,
    const int* __restrict__ nb, float* __restrict__ f1o, float* __restrict__ f2o,
    unsigned* __restrict__ su, double* __restrict__ sd)
{
    const int t = threadIdx.x;
    const int i = blockIdx.x*256 + t;
    unsigned uf1 = 0, uf1sq = 0;
    double df2 = 0.0, df2sq = 0.0;
    if (i < NN) {
        const int ci = center[i];
        const int* nbi = nb + i*KK;
        unsigned long long cnt = 0ull;        // 8 bits per class, max 16 each
        #pragma unroll
        for (int k=0;k<KK;++k) {
            int p = center[nbi[k]];
            cnt += 1ull << (p*8);
        }
        unsigned c1 = (unsigned)((cnt >> (ci*8)) & 0xFFull);
        float f2 = 0.f;
        #pragma unroll
        for (int c=0;c<CC;++c) {
            float fc = (float)((cnt >> (c*8)) & 0xFFull);
            fc = fmaxf(fc, 1e-5f);            // CLAMP
            f2 -= fc * logf(fc);
        }
        f1o[i] = (float)c1;
        f2o[i] = f2;
        uf1 = c1; uf1sq = c1*c1;
        df2 = (double)f2; df2sq = df2*df2;
    }
    #pragma unroll
    for (int off = 32; off > 0; off >>= 1) {
        uf1   += __shfl_down(uf1,   off, 64);
        uf1sq += __shfl_down(uf1sq, off, 64);
        df2   += __shfl_down(df2,   off, 64);
        df2sq += __shfl_down(df2sq, off, 64);
    }
    __shared__ unsigned r1[4], r1s[4];
    __shared__ double   r2[4], r2s[4];
    const int wid = t >> 6, lane = t & 63;
    if (lane == 0) { r1[wid]=uf1; r1s[wid]=uf1sq; r2[wid]=df2; r2s[wid]=df2sq; }
    __syncthreads();
    if (t == 0) {
        atomicAdd(&su[0], r1[0]+r1[1]+r1[2]+r1[3]);
        atomicAdd(&su[1], r1s[0]+r1s[1]+r1s[2]+r1s[3]);
        atomicAdd(&sd[0], r2[0]+r2[1]+r2[2]+r2[3]);
        atomicAdd(&sd[1], r2s[0]+r2s[1]+r2s[2]+r2s[3]);
    }
}

// ---------------- h_next = h + min(zold, z) * gather-sum(h); zold = z ----------------
__global__ __launch_bounds__(256) void k_update(const float4* __restrict__ Hin4,
    float4* __restrict__ Hout4, const int* __restrict__ nb,
    const float* __restrict__ f1, const float* __restrict__ f2,
    float* __restrict__ zold, const unsigned* __restrict__ su,
    const double* __restrict__ sd, const float* __restrict__ tau1,
    const float* __restrict__ tau2)
{
    const int t = threadIdx.x;
    const int node = blockIdx.x*8 + (t>>5);
    const int q = t & 31;
    if (node >= NN) return;
    const double invN = 1.0 / (double)NN;
    double mu1  = (double)su[0] * invN;
    double var1 = (double)su[1] * invN - mu1*mu1;
    double is1  = 1.0 / sqrt(var1 + 1e-5);
    double mu2  = sd[0] * invN;
    double var2 = sd[1] * invN - mu2*mu2;
    double is2  = 1.0 / sqrt(var2 + 1e-5);
    float nf1 = (float)(((double)f1[node] - mu1) * is1);
    float nf2 = (float)(((double)f2[node] - mu2) * is2);
    // sigmoid(-(nf - tau)) = 1/(1+exp(nf - tau))
    float z = (1.0f/(1.0f + expf(nf1 - tau1[0]))) * (1.0f/(1.0f + expf(nf2 - tau2[0])));
    float gate = fminf(zold[node], z);
    if (q == 0) zold[node] = z;

    const int* nbi = nb + node*KK;
    int idx[KK];
    #pragma unroll
    for (int k=0;k<KK;++k) idx[k] = nbi[k];
    float4 acc = make_float4(0.f,0.f,0.f,0.f);
    #pragma unroll
    for (int k=0;k<KK;++k) {
        float4 v = Hin4[(size_t)idx[k]*32 + q];
        acc.x += v.x; acc.y += v.y; acc.z += v.z; acc.w += v.w;
    }
    float4 h = Hin4[(size_t)node*32 + q];
    h.x += gate*acc.x; h.y += gate*acc.y; h.z += gate*acc.z; h.w += gate*acc.w;
    Hout4[(size_t)node*32 + q] = h;
}

// ---------------- out accum: sum_r h[r] * Wc[r, :] ----------------
__global__ __launch_bounds__(256) void k_final(const float* __restrict__ H,
    const float4* __restrict__ Wc4, double* __restrict__ oacc)
{
    const int t = threadIdx.x;
    float a[8];
    #pragma unroll
    for (int c=0;c<8;++c) a[c]=0.f;
    const int R = NN*DD;
    for (int r = blockIdx.x*256 + t; r < R; r += gridDim.x*256) {
        float h = H[r];
        float4 wa = Wc4[(size_t)r*2], wb = Wc4[(size_t)r*2 + 1];
        a[0]+=h*wa.x; a[1]+=h*wa.y; a[2]+=h*wa.z; a[3]+=h*wa.w;
        a[4]+=h*wb.x; a[5]+=h*wb.y; a[6]+=h*wb.z; a[7]+=h*wb.w;
    }
    #pragma unroll
    for (int off = 32; off > 0; off >>= 1)
        #pragma unroll
        for (int c=0;c<8;++c) a[c] += __shfl_down(a[c], off, 64);
    __shared__ double sred[4][8];
    const int wid = t >> 6, lane = t & 63;
    if (lane == 0) {
        #pragma unroll
        for (int c=0;c<8;++c) sred[wid][c] = (double)a[c];
    }
    __syncthreads();
    if (t < 8) {
        double s = sred[0][t]+sred[1][t]+sred[2][t]+sred[3][t];
        atomicAdd(&oacc[t], s);
    }
}

__global__ void k_fin(const double* __restrict__ oacc, const float* __restrict__ bc,
                      float* __restrict__ out)
{
    const int t = threadIdx.x;
    if (t < CC) out[t] = (float)(oacc[t] + (double)bc[t]);
}

extern "C" void kernel_launch(void* const* d_in, const int* in_sizes, int n_in,
                              void* d_out, int out_size, void* d_ws, size_t ws_size,
                              hipStream_t stream)
{
    const float* feat = (const float*)d_in[0];
    const float* Wg   = (const float*)d_in[1];
    const float* bg   = (const float*)d_in[2];
    const float* Wy   = (const float*)d_in[3];
    const float* by   = (const float*)d_in[4];
    const float* tau1 = (const float*)d_in[5];
    const float* tau2 = (const float*)d_in[6];
    const float* Wc   = (const float*)d_in[7];
    const float* bc   = (const float*)d_in[8];
    const int*   nb   = (const int*)d_in[9];

    char* ws = (char*)d_ws;
    float*    A      = (float*)(ws + A_OFF);
    float*    B      = (float*)(ws + B_OFF);
    int*      center = (int*)(ws + CENT_OFF);
    float*    zold   = (float*)(ws + ZOLD_OFF);
    float*    f1     = (float*)(ws + F1_OFF);
    float*    f2     = (float*)(ws + F2_OFF);
    unsigned* su     = (unsigned*)(ws + SU_OFF);
    double*   sd     = (double*)(ws + SD_OFF);
    double*   oacc   = (double*)(ws + OACC_OFF);

    k_gemm<<<(NN + 63)/64, 256, 0, stream>>>(feat, Wg, A, oacc);
    k_agg0<<<(NN + 7)/8, 256, 0, stream>>>((const float4*)A, nb, bg, (float4*)B, zold);

    float* hcur = B; float* hnext = A;
    for (int it = 0; it < 3; ++it) {
        k_center<<<(NN + 63)/64, 256, 0, stream>>>(hcur, Wy, by, center, su, sd);
        k_stats<<<(NN + 255)/256, 256, 0, stream>>>(center, nb, f1, f2, su, sd);
        k_update<<<(NN + 7)/8, 256, 0, stream>>>((const float4*)hcur, (float4*)hnext,
                                                 nb, f1, f2, zold, su, sd, tau1, tau2);
        float* tmp = hcur; hcur = hnext; hnext = tmp;
    }
    k_final<<<2048, 256, 0, stream>>>(hcur, (const float4*)Wc, oacc);
    k_fin<<<1, 64, 0, stream>>>(oacc, bc, (float*)d_out);
}

// Round 3
// 591.459 us; speedup vs baseline: 1.1222x; 1.1222x over previous
//
#include <hip/hip_runtime.h>
#include <math.h>

#define NN 50000
#define DD 128
#define KK 16
#define CC 8
#define NCH 4                 // chunks of 32 floats: h stored [NCH][NN][32]
#define NB_AGG 1563           // ceil(NN/32) node-blocks per chunk

// ---- ws layout (bytes) ----
#define A_OFF    0u
#define B_OFF    (NN*DD*4u)               // 25,600,000
#define CENT_OFF (2u*NN*DD*4u)            // 51,200,000
#define Z0_OFF   (CENT_OFF + NN*4u)
#define Z1_OFF   (Z0_OFF + NN*4u)
#define F1_OFF   (Z1_OFF + NN*4u)
#define F2_OFF   (F1_OFF + NN*4u)
#define SU_OFF   (F2_OFF + NN*4u)         // 2 x u32 (exact f1 sums)
#define SD_OFF   (SU_OFF + 8u)            // 2 x double (f2 sums)
#define OACC_OFF (SD_OFF + 16u)           // 8 x double (output accum)

// ---------------- feat @ W_gcn -> A (chunk-major [c][node][32]) ----------------
__global__ __launch_bounds__(256) void k_gemm(const float* __restrict__ feat,
    const float* __restrict__ W, float* __restrict__ A, double* __restrict__ oacc)
{
    __shared__ __align__(16) float sW[DD*DD];
    __shared__ float sF[64][DD+1];
    const int t = threadIdx.x;
    const int base = blockIdx.x * 64;
    if (blockIdx.x == 0 && t < CC) oacc[t] = 0.0;

    const float4* W4 = (const float4*)W;
    float4* sW4 = (float4*)sW;
    #pragma unroll
    for (int i = 0; i < 16; ++i) sW4[t + i*256] = W4[t + i*256];

    const float4* F4 = (const float4*)feat;
    #pragma unroll
    for (int e = t; e < 64*32; e += 256) {
        int row = e >> 5, q = e & 31;
        float4 v = make_float4(0.f,0.f,0.f,0.f);
        if (base + row < NN) v = F4[(size_t)(base + row)*32 + q];
        sF[row][q*4+0] = v.x; sF[row][q*4+1] = v.y;
        sF[row][q*4+2] = v.z; sF[row][q*4+3] = v.w;
    }
    __syncthreads();

    const int cg = t & 15;       // cols cg*8 .. cg*8+7
    const int ng = t >> 4;       // nodes ng*4 .. ng*4+3
    const int cb = cg * 8;
    float acc[4][8];
    #pragma unroll
    for (int j=0;j<4;++j)
        #pragma unroll
        for (int c=0;c<8;++c) acc[j][c]=0.f;

    #pragma unroll 4
    for (int d = 0; d < DD; ++d) {
        float4 wa = *(const float4*)&sW[d*DD + cb];
        float4 wb = *(const float4*)&sW[d*DD + cb + 4];
        #pragma unroll
        for (int j=0;j<4;++j) {
            float f = sF[ng*4+j][d];
            acc[j][0] += f*wa.x; acc[j][1] += f*wa.y;
            acc[j][2] += f*wa.z; acc[j][3] += f*wa.w;
            acc[j][4] += f*wb.x; acc[j][5] += f*wb.y;
            acc[j][6] += f*wb.z; acc[j][7] += f*wb.w;
        }
    }
    const int ch = cb >> 5;        // chunk of this 8-col group
    const int co = cb & 31;        // offset within chunk
    #pragma unroll
    for (int j=0;j<4;++j) {
        int node = base + ng*4 + j;
        if (node < NN) {
            float4* dst = (float4*)&A[((size_t)ch*NN + node)*32 + co];
            dst[0] = make_float4(acc[j][0],acc[j][1],acc[j][2],acc[j][3]);
            dst[1] = make_float4(acc[j][4],acc[j][5],acc[j][6],acc[j][7]);
        }
    }
}

// ---------------- h0 = gather-sum(A) + b_gcn (chunked); z0 = 1 ----------------
// grid = NCH * NB_AGG, chunk-major so each 6.4MB chunk stays L2-resident.
__global__ __launch_bounds__(256) void k_agg0(const float4* __restrict__ A4,
    const int* __restrict__ nb, const float* __restrict__ bg,
    float4* __restrict__ H4, float* __restrict__ zold)
{
    const int t = threadIdx.x;
    const int c = blockIdx.x / NB_AGG;
    const int nbase = (blockIdx.x % NB_AGG) * 32;
    __shared__ int sIdx[32*KK];
    if (t < 128) {
        if (nbase + (t >> 2) < NN)
            ((int4*)sIdx)[t] = ((const int4*)(nb + (size_t)nbase*KK))[t];
    }
    __syncthreads();
    const int nl = t >> 3;          // node-local 0..31
    const int q  = t & 7;           // float4 index within 32-float chunk row
    const int node = nbase + nl;
    if (node >= NN) return;
    float4 acc = ((const float4*)bg)[c*8 + q];
    #pragma unroll
    for (int k=0;k<KK;++k) {
        int idx = sIdx[nl*KK + k];                  // LDS broadcast
        float4 v = A4[((size_t)c*NN + idx)*8 + q];
        acc.x += v.x; acc.y += v.y; acc.z += v.z; acc.w += v.w;
    }
    H4[((size_t)c*NN + node)*8 + q] = acc;
    if (c == 0 && q == 0) zold[node] = 1.0f;
}

// ---------------- center = argmax(h@Wy+by) (softmax skipped: monotonic) ----------------
__global__ __launch_bounds__(256) void k_center(const float* __restrict__ H,
    const float* __restrict__ Wy, const float* __restrict__ by,
    int* __restrict__ center, unsigned* __restrict__ su, double* __restrict__ sd)
{
    const int t = threadIdx.x;
    if (blockIdx.x == 0) {          // zero the per-iteration stat accumulators
        if (t < 2) su[t] = 0u;
        if (t >= 2 && t < 4) sd[t-2] = 0.0;
    }
    __shared__ float sH[64][DD+1];
    __shared__ __align__(16) float sWy[DD*CC];
    __shared__ float sby[CC];
    const int base = blockIdx.x * 64;
    const float4* H4 = (const float4*)H;
    #pragma unroll
    for (int e = t; e < 64*32; e += 256) {
        int row = e >> 5, q = e & 31;
        int ch = q >> 3, q8 = q & 7;
        float4 v = make_float4(0.f,0.f,0.f,0.f);
        if (base + row < NN) v = H4[((size_t)ch*NN + base+row)*8 + q8];
        sH[row][q*4+0] = v.x; sH[row][q*4+1] = v.y;
        sH[row][q*4+2] = v.z; sH[row][q*4+3] = v.w;
    }
    ((float4*)sWy)[t] = ((const float4*)Wy)[t & 255];   // 256 float4 == 1024 floats
    if (t < CC) sby[t] = by[t];
    __syncthreads();

    const int nl = t >> 2;          // node-local 0..63
    const int c0 = (t & 3) * 2;     // this lane handles classes c0, c0+1
    float a0 = 0.f, a1 = 0.f;
    #pragma unroll 8
    for (int d = 0; d < DD; ++d) {
        float f = sH[nl][d];
        a0 += f * sWy[d*CC + c0];
        a1 += f * sWy[d*CC + c0 + 1];
    }
    a0 += sby[c0]; a1 += sby[c0+1];
    float bv = a0; int bi = c0;
    if (a1 > bv) { bv = a1; bi = c0 + 1; }
    #pragma unroll
    for (int off = 1; off < 4; off <<= 1) {
        float ov = __shfl_xor(bv, off, 64);
        int   oi = __shfl_xor(bi, off, 64);
        if (ov > bv || (ov == bv && oi < bi)) { bv = ov; bi = oi; }
    }
    const int node = base + nl;
    if ((t & 3) == 0 && node < NN) center[node] = bi;
}

// ---------------- f1, f2 per node + global sums (u32 exact / f64) ----------------
__global__ __launch_bounds__(256) void k_stats(const int* __restrict__ center,
    const int* __restrict__ nb, float* __restrict__ f1o, float* __restrict__ f2o,
    unsigned* __restrict__ su, double* __restrict__ sd)
{
    const int t = threadIdx.x;
    const int i = blockIdx.x*256 + t;
    unsigned uf1 = 0, uf1sq = 0;
    double df2 = 0.0, df2sq = 0.0;
    if (i < NN) {
        const int ci = center[i];
        const int* nbi = nb + i*KK;
        unsigned long long cnt = 0ull;        // 8 bits per class, max 16 each
        #pragma unroll
        for (int k=0;k<KK;++k) {
            int p = center[nbi[k]];
            cnt += 1ull << (p*8);
        }
        unsigned c1 = (unsigned)((cnt >> (ci*8)) & 0xFFull);
        float f2 = 0.f;
        #pragma unroll
        for (int c=0;c<CC;++c) {
            float fc = (float)((cnt >> (c*8)) & 0xFFull);
            fc = fmaxf(fc, 1e-5f);            // CLAMP
            f2 -= fc * logf(fc);
        }
        f1o[i] = (float)c1;
        f2o[i] = f2;
        uf1 = c1; uf1sq = c1*c1;
        df2 = (double)f2; df2sq = df2*df2;
    }
    #pragma unroll
    for (int off = 32; off > 0; off >>= 1) {
        uf1   += __shfl_down(uf1,   off, 64);
        uf1sq += __shfl_down(uf1sq, off, 64);
        df2   += __shfl_down(df2,   off, 64);
        df2sq += __shfl_down(df2sq, off, 64);
    }
    __shared__ unsigned r1[4], r1s[4];
    __shared__ double   r2[4], r2s[4];
    const int wid = t >> 6, lane = t & 63;
    if (lane == 0) { r1[wid]=uf1; r1s[wid]=uf1sq; r2[wid]=df2; r2s[wid]=df2sq; }
    __syncthreads();
    if (t == 0) {
        atomicAdd(&su[0], r1[0]+r1[1]+r1[2]+r1[3]);
        atomicAdd(&su[1], r1s[0]+r1s[1]+r1s[2]+r1s[3]);
        atomicAdd(&sd[0], r2[0]+r2[1]+r2[2]+r2[3]);
        atomicAdd(&sd[1], r2s[0]+r2s[1]+r2s[2]+r2s[3]);
    }
}

// ---------------- h_next = h + min(zold, z) * gather-sum(h) (chunked) ----------------
// grid = NCH * NB_AGG chunk-major. Reads zr (prev z), writes zw (new z) — ping-pong.
__global__ __launch_bounds__(256) void k_update(const float4* __restrict__ Hin4,
    float4* __restrict__ Hout4, const int* __restrict__ nb,
    const float* __restrict__ f1, const float* __restrict__ f2,
    const float* __restrict__ zr, float* __restrict__ zw,
    const unsigned* __restrict__ su, const double* __restrict__ sd,
    const float* __restrict__ tau1, const float* __restrict__ tau2)
{
    const int t = threadIdx.x;
    const int c = blockIdx.x / NB_AGG;
    const int nbase = (blockIdx.x % NB_AGG) * 32;
    __shared__ int sIdx[32*KK];
    if (t < 128) {
        if (nbase + (t >> 2) < NN)
            ((int4*)sIdx)[t] = ((const int4*)(nb + (size_t)nbase*KK))[t];
    }
    __syncthreads();
    const int nl = t >> 3;
    const int q  = t & 7;
    const int node = nbase + nl;
    if (node >= NN) return;

    const double invN = 1.0 / (double)NN;
    double mu1  = (double)su[0] * invN;
    double var1 = (double)su[1] * invN - mu1*mu1;
    double is1  = 1.0 / sqrt(var1 + 1e-5);
    double mu2  = sd[0] * invN;
    double var2 = sd[1] * invN - mu2*mu2;
    double is2  = 1.0 / sqrt(var2 + 1e-5);
    float nf1 = (float)(((double)f1[node] - mu1) * is1);
    float nf2 = (float)(((double)f2[node] - mu2) * is2);
    float z = (1.0f/(1.0f + expf(nf1 - tau1[0]))) * (1.0f/(1.0f + expf(nf2 - tau2[0])));
    float gate = fminf(zr[node], z);
    if (c == 0 && q == 0) zw[node] = z;

    float4 acc = make_float4(0.f,0.f,0.f,0.f);
    #pragma unroll
    for (int k=0;k<KK;++k) {
        int idx = sIdx[nl*KK + k];
        float4 v = Hin4[((size_t)c*NN + idx)*8 + q];
        acc.x += v.x; acc.y += v.y; acc.z += v.z; acc.w += v.w;
    }
    float4 h = Hin4[((size_t)c*NN + node)*8 + q];
    h.x += gate*acc.x; h.y += gate*acc.y; h.z += gate*acc.z; h.w += gate*acc.w;
    Hout4[((size_t)c*NN + node)*8 + q] = h;
}

// ---------------- out accum: sum_r h[r] * Wc[r, :] (h is chunk-major) ----------------
__global__ __launch_bounds__(256) void k_final(const float* __restrict__ H,
    const float4* __restrict__ Wc4, double* __restrict__ oacc)
{
    const int t = threadIdx.x;
    float a[8];
    #pragma unroll
    for (int c=0;c<8;++c) a[c]=0.f;
    const int R = NN*DD;
    for (int r = blockIdx.x*256 + t; r < R; r += gridDim.x*256) {
        int node = r >> 7, d = r & 127;
        float h = H[(((d>>5)*NN + node) << 5) + (d & 31)];
        float4 wa = Wc4[(size_t)r*2], wb = Wc4[(size_t)r*2 + 1];
        a[0]+=h*wa.x; a[1]+=h*wa.y; a[2]+=h*wa.z; a[3]+=h*wa.w;
        a[4]+=h*wb.x; a[5]+=h*wb.y; a[6]+=h*wb.z; a[7]+=h*wb.w;
    }
    #pragma unroll
    for (int off = 32; off > 0; off >>= 1)
        #pragma unroll
        for (int c=0;c<8;++c) a[c] += __shfl_down(a[c], off, 64);
    __shared__ double sred[4][8];
    const int wid = t >> 6, lane = t & 63;
    if (lane == 0) {
        #pragma unroll
        for (int c=0;c<8;++c) sred[wid][c] = (double)a[c];
    }
    __syncthreads();
    if (t < 8) {
        double s = sred[0][t]+sred[1][t]+sred[2][t]+sred[3][t];
        atomicAdd(&oacc[t], s);
    }
}

__global__ void k_fin(const double* __restrict__ oacc, const float* __restrict__ bc,
                      float* __restrict__ out)
{
    const int t = threadIdx.x;
    if (t < CC) out[t] = (float)(oacc[t] + (double)bc[t]);
}

extern "C" void kernel_launch(void* const* d_in, const int* in_sizes, int n_in,
                              void* d_out, int out_size, void* d_ws, size_t ws_size,
                              hipStream_t stream)
{
    const float* feat = (const float*)d_in[0];
    const float* Wg   = (const float*)d_in[1];
    const float* bg   = (const float*)d_in[2];
    const float* Wy   = (const float*)d_in[3];
    const float* by   = (const float*)d_in[4];
    const float* tau1 = (const float*)d_in[5];
    const float* tau2 = (const float*)d_in[6];
    const float* Wc   = (const float*)d_in[7];
    const float* bc   = (const float*)d_in[8];
    const int*   nb   = (const int*)d_in[9];

    char* ws = (char*)d_ws;
    float*    A      = (float*)(ws + A_OFF);
    float*    B      = (float*)(ws + B_OFF);
    int*      center = (int*)(ws + CENT_OFF);
    float*    z0     = (float*)(ws + Z0_OFF);
    float*    z1     = (float*)(ws + Z1_OFF);
    float*    f1     = (float*)(ws + F1_OFF);
    float*    f2     = (float*)(ws + F2_OFF);
    unsigned* su     = (unsigned*)(ws + SU_OFF);
    double*   sd     = (double*)(ws + SD_OFF);
    double*   oacc   = (double*)(ws + OACC_OFF);

    k_gemm<<<(NN + 63)/64, 256, 0, stream>>>(feat, Wg, A, oacc);
    k_agg0<<<NCH*NB_AGG, 256, 0, stream>>>((const float4*)A, nb, bg, (float4*)B, z0);

    float* hcur = B; float* hnext = A;
    float* zcur = z0; float* znext = z1;
    for (int it = 0; it < 3; ++it) {
        k_center<<<(NN + 63)/64, 256, 0, stream>>>(hcur, Wy, by, center, su, sd);
        k_stats<<<(NN + 255)/256, 256, 0, stream>>>(center, nb, f1, f2, su, sd);
        k_update<<<NCH*NB_AGG, 256, 0, stream>>>((const float4*)hcur, (float4*)hnext,
                                                 nb, f1, f2, zcur, znext, su, sd, tau1, tau2);
        float* tmp = hcur; hcur = hnext; hnext = tmp;
        tmp = zcur; zcur = znext; znext = tmp;
    }
    k_final<<<2048, 256, 0, stream>>>(hcur, (const float4*)Wc, oacc);
    k_fin<<<1, 64, 0, stream>>>(oacc, bc, (float*)d_out);
}